// Round 1
// baseline (155.325 us; speedup 1.0000x reference)
//
#include <hip/hip_runtime.h>
#include <hip/hip_fp16.h>
#include <math.h>

#define BB 8
#define CC 64
#define HH 128
#define WW 128
#define HO 64
#define WO 128
#define OC 64
#define HW (HH * WW)

typedef __attribute__((ext_vector_type(4))) float floatx4;
typedef __attribute__((ext_vector_type(8))) _Float16 half8;

__device__ __forceinline__ unsigned short f2h(float f) {
    __half h = __float2half(f);
    return __builtin_bit_cast(unsigned short, h);
}
__device__ __forceinline__ unsigned int packpair(float a, float b) {
    __half2 h = __floats2half2_rn(a, b);   // v_cvt_pkrtz_f16_f32, lo=a hi=b
    return __builtin_bit_cast(unsigned int, h);
}
// Barrier that drains ONLY LDS ops: global loads stay in flight across it.
// (default __syncthreads emits s_waitcnt vmcnt(0) -> 9 full gather-latency
// exposures per block; this is the main fix of this round)
__device__ __forceinline__ void lgkm_barrier() {
    asm volatile("s_waitcnt lgkmcnt(0)" ::: "memory");
    __builtin_amdgcn_s_barrier();
}

// ---------------------------------------------------------------------------
// Kernel A (prep), rewritten lean:
//  blocks 0..2047   : transpose x -> xP[b][y][w][c] = (f16 col w, f16 col w+1)
//                     pairs. float4 loads, LDS transpose (odd stride 77 ->
//                     conflict-free column reads), uint4-wide coalesced
//                     stores. xT stream DROPPED (fused stages from xP lows).
//  blocks 2048..2119: Wom[32][576] f16  (offset+mask GEMM weights, zero-pad)
//  blocks 2120..2263: W2[k][o][c] f16   (main conv MFMA A-operand layout)
// ---------------------------------------------------------------------------
__global__ __launch_bounds__(256) void prep(
    const float* __restrict__ x,
    const float* __restrict__ w_off, const float* __restrict__ w_msk,
    const float* __restrict__ w_conv,
    unsigned int* __restrict__ xP,
    unsigned short* __restrict__ Wom, unsigned short* __restrict__ W2)
{
    __shared__ float T[64][77];        // odd stride: col reads conflict-free
    int tid = threadIdx.x, bx = blockIdx.x;
    if (bx < 2048) {
        int wh = bx & 1, b = (bx >> 1) & 7, y = bx >> 4;
        int w0 = wh << 6;
        const float* xb = x + (((size_t)b * CC) * HH + y) * WW + w0;
        // phase A: 64 ch x 64 w as float4 (coalesced 1KB/wave-instr)
#pragma unroll
        for (int i = 0; i < 4; ++i) {
            int idx = i * 256 + tid;             // 0..1023
            int cch = idx >> 4, f4 = (idx & 15) << 2;
            floatx4 v = *(const floatx4*)(xb + (size_t)cch * HW + f4);
            T[cch][f4 + 0] = v.x;
            T[cch][f4 + 1] = v.y;
            T[cch][f4 + 2] = v.z;
            T[cch][f4 + 3] = v.w;
        }
        // extra column w0+64 (partner of pair at w0+63); 0 past right edge
        if (tid < 64) {
            float e = 0.0f;
            if (w0 + 64 < WW) e = xb[(size_t)tid * HW + 64];
            T[tid][64] = e;
        }
        __syncthreads();
        // phase B: lane=channel, wave owns 16 w-columns; packed-pair stores,
        // 64 lanes x 4B contiguous per store (256B)
        int ch = tid & 63;
        int wb = (tid >> 6) << 4;
        size_t base = ((((size_t)b * HH + y) * WW) + w0 + wb) * 64 + ch;
#pragma unroll
        for (int j = 0; j < 4; ++j) {
            int wl = wb + 4 * j;
            float a0 = T[ch][wl + 0];
            float a1 = T[ch][wl + 1];
            float a2 = T[ch][wl + 2];
            float a3 = T[ch][wl + 3];
            float a4 = T[ch][wl + 4];
            xP[base + (size_t)(4 * j + 0) * 64] = packpair(a0, a1);
            xP[base + (size_t)(4 * j + 1) * 64] = packpair(a1, a2);
            xP[base + (size_t)(4 * j + 2) * 64] = packpair(a2, a3);
            xP[base + (size_t)(4 * j + 3) * 64] = packpair(a3, a4);
        }
    } else if (bx < 2120) {
        int i = (bx - 2048) * 256 + tid;     // < 18432 = 32*576
        int chn = i / 576, kk = i % 576;
        int xs = kk >> 6, cc = kk & 63;
        float v = 0.0f;
        if (chn < 18)      v = w_off[(chn * CC + cc) * 9 + xs];
        else if (chn < 27) v = w_msk[((chn - 18) * CC + cc) * 9 + xs];
        Wom[i] = f2h(v);
    } else {
        int i = (bx - 2120) * 256 + tid;     // < 36864
        int k = i % 9, cc = (i / 9) % CC, o = i / (CC * 9);
        W2[((size_t)k * OC + o) * CC + cc] = f2h(w_conv[i]);
    }
}

// ---------------------------------------------------------------------------
// Kernel B: fused om-GEMM + coeff epilogue + deformable sampling + main MFMA.
// All fp16. Phases (LDS overlaid, 18304 B):
//  1. stage Xs[3][34][72] f16 from xP lows            (bytes 0..14688)
//  2. om GEMM (18 MFMA) -> omr[27][33]                (bytes 14720..18284)
//  3. epilogue -> metaC[288] {h2 coeffs} @8192, metaR[288] {row byte offs}
//     @10496 (overlay dead Xs bytes)
//  4. 9-tap loop: 2-deep gather pipeline (issue k+2 while storing k+1),
//     lgkm-only barriers (gathers stay in flight), v_pk_fma_f16 blend,
//     SGPR-base saddr gathers, double-buffered S @0..8192.
// ---------------------------------------------------------------------------
__global__ __launch_bounds__(256, 8) void fused(
    const unsigned int* __restrict__ xP,
    const unsigned short* __restrict__ Wom, const unsigned short* __restrict__ W2,
    const float* __restrict__ b_off, const float* __restrict__ b_msk,
    float* __restrict__ out)
{
    __shared__ __align__(16) char lds[18304];
    typedef _Float16 XsRow[34][72];
    XsRow* Xs = (XsRow*)lds;                                        // [3][34][72]
    unsigned short (*S)[32][64] = (unsigned short(*)[32][64])lds;   // [2][32][64]
    uint2* metaC = (uint2*)(lds + 8192);                            // 288*8
    uint2* metaR = (uint2*)(lds + 10496);                           // 288*8
    float (*omr)[33] = (float(*)[33])(lds + 14720);                 // [27][33]

    int tid = threadIdx.x;
    int lane = tid & 63;
    int wv = __builtin_amdgcn_readfirstlane(tid >> 6);
    int bx = blockIdx.x;               // 2048 = 8b * 64h * 4wt
    int b = bx & 7;
    int rest = bx >> 3;
    int h = rest >> 2;
    int w0 = (rest & 3) * 32;
    int h2 = 2 * h - 1;
    int m16 = lane & 15, q = lane >> 4;

    const unsigned int* xPb_u = xP + (size_t)b * HW * 64;

    // ---- phase 1: stage slab from xP pair-lows (uint4 coalesced) ----
    for (int u = tid; u < 1632; u += 256) {      // 1632 = 3*34*16
        int ky = u / 544;
        int rem = u - ky * 544;
        int col = rem >> 4, c4 = rem & 15;
        int hy = h2 + ky, wc = w0 - 1 + col;
        unsigned int lo0 = 0u, lo1 = 0u;
        if ((unsigned)hy < (unsigned)HH && (unsigned)wc < (unsigned)WW) {
            const uint4 g = *(const uint4*)(xPb_u + ((size_t)hy * WW + wc) * 64 + c4 * 4);
            lo0 = (g.x & 0xffffu) | (g.y << 16);
            lo1 = (g.z & 0xffffu) | (g.w << 16);
        }
        uint2* dst = (uint2*)((unsigned short*)lds + ((ky * 34 + col) * 72 + c4 * 4));
        *dst = make_uint2(lo0, lo1);
    }
    lgkm_barrier();

    // ---- phase 2: om GEMM (wave = 2 Mtiles x 2 Ntiles, K=576) ----
    {
        int mt = wv & 1, nt = wv >> 1;
        floatx4 a = (floatx4){0.f, 0.f, 0.f, 0.f};
        const _Float16* wa = (const _Float16*)Wom + (mt * 16 + m16) * 576 + q * 8;
#pragma unroll
        for (int t = 0; t < 18; ++t) {
            int xs = t >> 1, ky = xs / 3, kx = xs % 3;
            half8 af = *(const half8*)(wa + t * 32);
            half8 bf = *(const half8*)&Xs[ky][nt * 16 + m16 + kx][(t & 1) * 32 + q * 8];
            a = __builtin_amdgcn_mfma_f32_16x16x32_f16(af, bf, a, 0, 0, 0);
        }
#pragma unroll
        for (int r = 0; r < 4; ++r) {
            int chn = mt * 16 + q * 4 + r;
            if (chn < 27) omr[chn][nt * 16 + m16] = a[r];
        }
    }
    lgkm_barrier();   // omr ready; Xs reads done (meta/S may overlay)

    // ---- phase 3: coeffs (half2) + packed row byte-offsets per (tap,pos) ----
    for (int u = tid; u < 288; u += 256) {
        int kk = u >> 5, pos = u & 31;
        float offy = omr[2 * kk][pos] + b_off[2 * kk];
        float offx = omr[2 * kk + 1][pos] + b_off[2 * kk + 1];
        float mk = 1.0f / (1.0f + __expf(-(omr[18 + kk][pos] + b_msk[kk])));
        float py = offy + (float)(kk / 3) + (float)h2;
        float px = offx + (float)(kk % 3) + (float)(w0 + pos - 1);

        float y0f = floorf(py), x0f = floorf(px);
        float dy = py - y0f, dx = px - x0f;
        int y0 = (int)y0f, x0 = (int)x0f;
        int y1 = y0 + 1, x1 = x0 + 1;
        bool vy0 = (unsigned)y0 < (unsigned)HH;
        bool vy1 = (unsigned)y1 < (unsigned)HH;
        bool vx0 = (unsigned)x0 < (unsigned)WW;
        bool vx1 = (unsigned)x1 < (unsigned)WW;
        float w00 = (1.0f - dy) * (1.0f - dx) * ((vy0 && vx0) ? mk : 0.0f);
        float w01 = (1.0f - dy) * dx          * ((vy0 && vx1) ? mk : 0.0f);
        float w10 = dy * (1.0f - dx)          * ((vy1 && vx0) ? mk : 0.0f);
        float w11 = dy * dx                   * ((vy1 && vx1) ? mk : 0.0f);
        int xbase = min(max(x0, 0), WW - 2);
        bool s0 = x0 > xbase;
        bool s1 = x1 > xbase;
        float cxA = (s0 ? 0.f : w00) + (s1 ? 0.f : w01);
        float cyA = (s0 ? w00 : 0.f) + (s1 ? w01 : 0.f);
        float cxB = (s0 ? 0.f : w10) + (s1 ? 0.f : w11);
        float cyB = (s0 ? w10 : 0.f) + (s1 ? w11 : 0.f);
        int yc0 = min(max(y0, 0), HH - 1);
        int yc1 = min(max(y1, 0), HH - 1);

        __half2 hA = __floats2half2_rn(cxA, cyA);
        __half2 hB = __floats2half2_rn(cxB, cyB);
        metaC[u] = make_uint2(__builtin_bit_cast(unsigned int, hA),
                              __builtin_bit_cast(unsigned int, hB));
        metaR[u] = make_uint2((unsigned)(yc0 * WW + xbase) * 256u,
                              (unsigned)(yc1 * WW + xbase) * 256u);
    }
    lgkm_barrier();

    // ---- phase 4: 2-deep pipelined sampling + main MFMA ----
    int p0 = wv * 8;                   // my 8 positions
    const char* xPb = (const char*)xPb_u;
    unsigned int voff = 4u * (unsigned)lane;
    floatx4 acc0 = (floatx4){0.f, 0.f, 0.f, 0.f};
    floatx4 acc1 = (floatx4){0.f, 0.f, 0.f, 0.f};

    unsigned int Ga0[8], Ga1[8], Gb0[8], Gb1[8];

    auto issue = [&](int k, unsigned int (&A0)[8], unsigned int (&A1)[8]) {
#pragma unroll
        for (int i = 0; i < 8; ++i) {
            uint2 zw = metaR[k * 32 + p0 + i];           // broadcast ds_read_b64
            const char* r0 = xPb + (unsigned)__builtin_amdgcn_readfirstlane((int)zw.x);
            const char* r1 = xPb + (unsigned)__builtin_amdgcn_readfirstlane((int)zw.y);
            A0[i] = *(const unsigned int*)(r0 + voff);   // saddr + shared voffset
            A1[i] = *(const unsigned int*)(r1 + voff);
        }
    };
    auto dostore = [&](int k, int buf, unsigned int (&A0)[8], unsigned int (&A1)[8]) {
#pragma unroll
        for (int i = 0; i < 8; ++i) {
            uint2 cf = metaC[k * 32 + p0 + i];           // broadcast ds_read_b64
            __half2 hA = __builtin_bit_cast(__half2, cf.x);
            __half2 hB = __builtin_bit_cast(__half2, cf.y);
            __half2 g0 = __builtin_bit_cast(__half2, A0[i]);
            __half2 g1 = __builtin_bit_cast(__half2, A1[i]);
            __half2 p = __hfma2(hA, g0, __hmul2(hB, g1));   // v_pk_fma_f16
            __half sv = __hadd(__low2half(p), __high2half(p));
            int pos = p0 + i;
            S[buf][pos][((lane >> 3) ^ (pos & 7)) * 8 + (lane & 7)] =
                __builtin_bit_cast(unsigned short, sv);
        }
    };
    auto mfma_step = [&](int k, int buf) {
        const _Float16* wk = (const _Float16*)W2
            + ((size_t)(k * OC) + wv * 16 + m16) * CC + q * 8;
#pragma unroll
        for (int s = 0; s < 2; ++s) {
            half8 af = *(const half8*)(wk + s * 32);
            int cb = ((q + 4 * s) ^ (m16 & 7)) * 8;
            half8 bf0 = *(const half8*)&S[buf][m16][cb];
            half8 bf1 = *(const half8*)&S[buf][16 + m16][cb];
            acc0 = __builtin_amdgcn_mfma_f32_16x16x32_f16(af, bf0, acc0, 0, 0, 0);
            acc1 = __builtin_amdgcn_mfma_f32_16x16x32_f16(af, bf1, acc1, 0, 0, 0);
        }
    };

    issue(0, Ga0, Ga1);
    dostore(0, 0, Ga0, Ga1);           // prologue: one vmcnt stall, only here
    issue(1, Gb0, Gb1);
#pragma unroll
    for (int k = 0; k < 9; ++k) {
        lgkm_barrier();                // S[k&1] visible; gathers keep flying
        mfma_step(k, k & 1);
        if ((k & 1) == 0) {
            if (k < 7) issue(k + 2, Ga0, Ga1);      // buf (k+2)&1 == 0
            if (k < 8) dostore(k + 1, (k + 1) & 1, Gb0, Gb1);
        } else {
            if (k < 7) issue(k + 2, Gb0, Gb1);
            if (k < 8) dostore(k + 1, (k + 1) & 1, Ga0, Ga1);
        }
    }

    // epilogue: C/D col=lane&15 (pos), row=(lane>>4)*4+reg (o)
#pragma unroll
    for (int nt = 0; nt < 2; ++nt) {
        floatx4 av = nt ? acc1 : acc0;
#pragma unroll
        for (int r = 0; r < 4; ++r) {
            int o = wv * 16 + q * 4 + r;
            out[(((size_t)b * OC + o) * HO + h) * WO + w0 + nt * 16 + m16] = av[r];
        }
    }
}

// ---------------------------------------------------------------------------
extern "C" void kernel_launch(void* const* d_in, const int* in_sizes, int n_in,
                              void* d_out, int out_size, void* d_ws, size_t ws_size,
                              hipStream_t stream)
{
    const float* x      = (const float*)d_in[0];
    const float* w_off  = (const float*)d_in[1];
    const float* b_off  = (const float*)d_in[2];
    const float* w_msk  = (const float*)d_in[3];
    const float* b_msk  = (const float*)d_in[4];
    const float* w_conv = (const float*)d_in[5];
    float* out = (float*)d_out;

    // workspace (~33.7 MB): xP f16-pair uints, Wom, W2   (xT dropped)
    unsigned int* xP = (unsigned int*)d_ws;                       // 8*HW*64 * 4B
    unsigned short* Wom = (unsigned short*)(xP + (size_t)BB * HW * 64); // 32*576
    unsigned short* W2 = Wom + 32 * 576;                          // 36864

    prep<<<dim3(2264), dim3(256), 0, stream>>>(x, w_off, w_msk, w_conv,
                                               xP, Wom, W2);
    fused<<<dim3(2048), dim3(256), 0, stream>>>(xP, Wom, W2,
                                                b_off, b_msk, out);
}

// Round 2
// 145.578 us; speedup vs baseline: 1.0670x; 1.0670x over previous
//
#include <hip/hip_runtime.h>
#include <hip/hip_fp16.h>
#include <math.h>

#define BB 8
#define CC 64
#define HH 128
#define WW 128
#define HO 64
#define WO 128
#define OC 64
#define HW (HH * WW)

typedef __attribute__((ext_vector_type(4))) float floatx4;
typedef __attribute__((ext_vector_type(8))) _Float16 half8;

__device__ __forceinline__ unsigned short f2h(float f) {
    __half h = __float2half(f);
    return __builtin_bit_cast(unsigned short, h);
}
__device__ __forceinline__ unsigned int packpair(float a, float b) {
    __half2 h = __floats2half2_rn(a, b);   // v_cvt_pkrtz_f16_f32, lo=a hi=b
    return __builtin_bit_cast(unsigned int, h);
}
// Barrier that drains ONLY LDS ops: global loads stay in flight across it.
__device__ __forceinline__ void lgkm_barrier() {
    asm volatile("s_waitcnt lgkmcnt(0)" ::: "memory");
    __builtin_amdgcn_s_barrier();
}

// ---------------------------------------------------------------------------
// Kernel A (prep):
//  blocks 0..2047   : transpose x -> xP[b][y][w][c] = (f16 col w, f16 col w+1)
//  blocks 2048..2119: Wom[32][576] f16  (offset+mask GEMM weights, zero-pad)
//  blocks 2120..2263: W2[k][o][c] f16   (main conv MFMA A-operand layout)
// ---------------------------------------------------------------------------
__global__ __launch_bounds__(256) void prep(
    const float* __restrict__ x,
    const float* __restrict__ w_off, const float* __restrict__ w_msk,
    const float* __restrict__ w_conv,
    unsigned int* __restrict__ xP,
    unsigned short* __restrict__ Wom, unsigned short* __restrict__ W2)
{
    __shared__ float T[64][77];        // odd stride: col reads conflict-free
    int tid = threadIdx.x, bx = blockIdx.x;
    if (bx < 2048) {
        int wh = bx & 1, b = (bx >> 1) & 7, y = bx >> 4;
        int w0 = wh << 6;
        const float* xb = x + (((size_t)b * CC) * HH + y) * WW + w0;
#pragma unroll
        for (int i = 0; i < 4; ++i) {
            int idx = i * 256 + tid;             // 0..1023
            int cch = idx >> 4, f4 = (idx & 15) << 2;
            floatx4 v = *(const floatx4*)(xb + (size_t)cch * HW + f4);
            T[cch][f4 + 0] = v.x;
            T[cch][f4 + 1] = v.y;
            T[cch][f4 + 2] = v.z;
            T[cch][f4 + 3] = v.w;
        }
        if (tid < 64) {
            float e = 0.0f;
            if (w0 + 64 < WW) e = xb[(size_t)tid * HW + 64];
            T[tid][64] = e;
        }
        __syncthreads();
        int ch = tid & 63;
        int wb = (tid >> 6) << 4;
        size_t base = ((((size_t)b * HH + y) * WW) + w0 + wb) * 64 + ch;
#pragma unroll
        for (int j = 0; j < 4; ++j) {
            int wl = wb + 4 * j;
            float a0 = T[ch][wl + 0];
            float a1 = T[ch][wl + 1];
            float a2 = T[ch][wl + 2];
            float a3 = T[ch][wl + 3];
            float a4 = T[ch][wl + 4];
            xP[base + (size_t)(4 * j + 0) * 64] = packpair(a0, a1);
            xP[base + (size_t)(4 * j + 1) * 64] = packpair(a1, a2);
            xP[base + (size_t)(4 * j + 2) * 64] = packpair(a2, a3);
            xP[base + (size_t)(4 * j + 3) * 64] = packpair(a3, a4);
        }
    } else if (bx < 2120) {
        int i = (bx - 2048) * 256 + tid;     // < 18432 = 32*576
        int chn = i / 576, kk = i % 576;
        int xs = kk >> 6, cc = kk & 63;
        float v = 0.0f;
        if (chn < 18)      v = w_off[(chn * CC + cc) * 9 + xs];
        else if (chn < 27) v = w_msk[((chn - 18) * CC + cc) * 9 + xs];
        Wom[i] = f2h(v);
    } else {
        int i = (bx - 2120) * 256 + tid;     // < 36864
        int k = i % 9, cc = (i / 9) % CC, o = i / (CC * 9);
        W2[((size_t)k * OC + o) * CC + cc] = f2h(w_conv[i]);
    }
}

// ---------------------------------------------------------------------------
// Kernel B: fused om-GEMM + coeff epilogue + deformable sampling + main MFMA.
// All fp16. lgkm-only barriers; 2-deep gather pipeline.
// __launch_bounds__(256,4): 128-VGPR budget -> pipeline arrays stay in
// registers (round-1's (256,8) capped at 64 VGPR -> 42 MB scratch spill).
// ---------------------------------------------------------------------------
__global__ __launch_bounds__(256, 4) void fused(
    const unsigned int* __restrict__ xP,
    const unsigned short* __restrict__ Wom, const unsigned short* __restrict__ W2,
    const float* __restrict__ b_off, const float* __restrict__ b_msk,
    float* __restrict__ out)
{
    __shared__ __align__(16) char lds[18304];
    typedef _Float16 XsRow[34][72];
    XsRow* Xs = (XsRow*)lds;                                        // [3][34][72]
    unsigned short (*S)[32][64] = (unsigned short(*)[32][64])lds;   // [2][32][64]
    uint2* metaC = (uint2*)(lds + 8192);                            // 288*8
    uint2* metaR = (uint2*)(lds + 10496);                           // 288*8
    float (*omr)[33] = (float(*)[33])(lds + 14720);                 // [27][33]

    int tid = threadIdx.x;
    int lane = tid & 63;
    int wv = __builtin_amdgcn_readfirstlane(tid >> 6);
    int bx = blockIdx.x;               // 2048 = 8b * 64h * 4wt
    int b = bx & 7;
    int rest = bx >> 3;
    int h = rest >> 2;
    int w0 = (rest & 3) * 32;
    int h2 = 2 * h - 1;
    int m16 = lane & 15, q = lane >> 4;

    const unsigned int* xPb_u = xP + (size_t)b * HW * 64;

    // ---- phase 1: stage slab from xP pair-lows (uint4 coalesced) ----
    for (int u = tid; u < 1632; u += 256) {      // 1632 = 3*34*16
        int ky = u / 544;
        int rem = u - ky * 544;
        int col = rem >> 4, c4 = rem & 15;
        int hy = h2 + ky, wc = w0 - 1 + col;
        unsigned int lo0 = 0u, lo1 = 0u;
        if ((unsigned)hy < (unsigned)HH && (unsigned)wc < (unsigned)WW) {
            const uint4 g = *(const uint4*)(xPb_u + ((size_t)hy * WW + wc) * 64 + c4 * 4);
            lo0 = (g.x & 0xffffu) | (g.y << 16);
            lo1 = (g.z & 0xffffu) | (g.w << 16);
        }
        uint2* dst = (uint2*)((unsigned short*)lds + ((ky * 34 + col) * 72 + c4 * 4));
        *dst = make_uint2(lo0, lo1);
    }
    lgkm_barrier();

    // ---- phase 2: om GEMM (wave = 2 Mtiles x 2 Ntiles, K=576) ----
    {
        int mt = wv & 1, nt = wv >> 1;
        floatx4 a = (floatx4){0.f, 0.f, 0.f, 0.f};
        const _Float16* wa = (const _Float16*)Wom + (mt * 16 + m16) * 576 + q * 8;
#pragma unroll
        for (int t = 0; t < 18; ++t) {
            int xs = t >> 1, ky = xs / 3, kx = xs % 3;
            half8 af = *(const half8*)(wa + t * 32);
            half8 bf = *(const half8*)&Xs[ky][nt * 16 + m16 + kx][(t & 1) * 32 + q * 8];
            a = __builtin_amdgcn_mfma_f32_16x16x32_f16(af, bf, a, 0, 0, 0);
        }
#pragma unroll
        for (int r = 0; r < 4; ++r) {
            int chn = mt * 16 + q * 4 + r;
            if (chn < 27) omr[chn][nt * 16 + m16] = a[r];
        }
    }
    lgkm_barrier();   // omr ready; Xs reads done (meta/S may overlay)

    // ---- phase 3: coeffs (half2) + packed row byte-offsets per (tap,pos) ----
    for (int u = tid; u < 288; u += 256) {
        int kk = u >> 5, pos = u & 31;
        float offy = omr[2 * kk][pos] + b_off[2 * kk];
        float offx = omr[2 * kk + 1][pos] + b_off[2 * kk + 1];
        float mk = 1.0f / (1.0f + __expf(-(omr[18 + kk][pos] + b_msk[kk])));
        float py = offy + (float)(kk / 3) + (float)h2;
        float px = offx + (float)(kk % 3) + (float)(w0 + pos - 1);

        float y0f = floorf(py), x0f = floorf(px);
        float dy = py - y0f, dx = px - x0f;
        int y0 = (int)y0f, x0 = (int)x0f;
        int y1 = y0 + 1, x1 = x0 + 1;
        bool vy0 = (unsigned)y0 < (unsigned)HH;
        bool vy1 = (unsigned)y1 < (unsigned)HH;
        bool vx0 = (unsigned)x0 < (unsigned)WW;
        bool vx1 = (unsigned)x1 < (unsigned)WW;
        float w00 = (1.0f - dy) * (1.0f - dx) * ((vy0 && vx0) ? mk : 0.0f);
        float w01 = (1.0f - dy) * dx          * ((vy0 && vx1) ? mk : 0.0f);
        float w10 = dy * (1.0f - dx)          * ((vy1 && vx0) ? mk : 0.0f);
        float w11 = dy * dx                   * ((vy1 && vx1) ? mk : 0.0f);
        int xbase = min(max(x0, 0), WW - 2);
        bool s0 = x0 > xbase;
        bool s1 = x1 > xbase;
        float cxA = (s0 ? 0.f : w00) + (s1 ? 0.f : w01);
        float cyA = (s0 ? w00 : 0.f) + (s1 ? w01 : 0.f);
        float cxB = (s0 ? 0.f : w10) + (s1 ? 0.f : w11);
        float cyB = (s0 ? w10 : 0.f) + (s1 ? w11 : 0.f);
        int yc0 = min(max(y0, 0), HH - 1);
        int yc1 = min(max(y1, 0), HH - 1);

        __half2 hA = __floats2half2_rn(cxA, cyA);
        __half2 hB = __floats2half2_rn(cxB, cyB);
        metaC[u] = make_uint2(__builtin_bit_cast(unsigned int, hA),
                              __builtin_bit_cast(unsigned int, hB));
        metaR[u] = make_uint2((unsigned)(yc0 * WW + xbase) * 256u,
                              (unsigned)(yc1 * WW + xbase) * 256u);
    }
    lgkm_barrier();

    // ---- phase 4: 2-deep pipelined sampling + main MFMA ----
    int p0 = wv * 8;                   // my 8 positions
    const char* xPb = (const char*)xPb_u;
    unsigned int voff = 4u * (unsigned)lane;
    floatx4 acc0 = (floatx4){0.f, 0.f, 0.f, 0.f};
    floatx4 acc1 = (floatx4){0.f, 0.f, 0.f, 0.f};

    unsigned int Ga0[8], Ga1[8], Gb0[8], Gb1[8];

    auto issue = [&](int k, unsigned int (&A0)[8], unsigned int (&A1)[8]) {
#pragma unroll
        for (int i = 0; i < 8; ++i) {
            uint2 zw = metaR[k * 32 + p0 + i];           // broadcast ds_read_b64
            const char* r0 = xPb + (unsigned)__builtin_amdgcn_readfirstlane((int)zw.x);
            const char* r1 = xPb + (unsigned)__builtin_amdgcn_readfirstlane((int)zw.y);
            A0[i] = *(const unsigned int*)(r0 + voff);   // saddr + shared voffset
            A1[i] = *(const unsigned int*)(r1 + voff);
        }
    };
    auto dostore = [&](int k, int buf, unsigned int (&A0)[8], unsigned int (&A1)[8]) {
#pragma unroll
        for (int i = 0; i < 8; ++i) {
            uint2 cf = metaC[k * 32 + p0 + i];           // broadcast ds_read_b64
            __half2 hA = __builtin_bit_cast(__half2, cf.x);
            __half2 hB = __builtin_bit_cast(__half2, cf.y);
            __half2 g0 = __builtin_bit_cast(__half2, A0[i]);
            __half2 g1 = __builtin_bit_cast(__half2, A1[i]);
            __half2 p = __hfma2(hA, g0, __hmul2(hB, g1));   // v_pk_fma_f16
            __half sv = __hadd(__low2half(p), __high2half(p));
            int pos = p0 + i;
            S[buf][pos][((lane >> 3) ^ (pos & 7)) * 8 + (lane & 7)] =
                __builtin_bit_cast(unsigned short, sv);
        }
    };
    auto mfma_step = [&](int k, int buf) {
        const _Float16* wk = (const _Float16*)W2
            + ((size_t)(k * OC) + wv * 16 + m16) * CC + q * 8;
#pragma unroll
        for (int s = 0; s < 2; ++s) {
            half8 af = *(const half8*)(wk + s * 32);
            int cb = ((q + 4 * s) ^ (m16 & 7)) * 8;
            half8 bf0 = *(const half8*)&S[buf][m16][cb];
            half8 bf1 = *(const half8*)&S[buf][16 + m16][cb];
            acc0 = __builtin_amdgcn_mfma_f32_16x16x32_f16(af, bf0, acc0, 0, 0, 0);
            acc1 = __builtin_amdgcn_mfma_f32_16x16x32_f16(af, bf1, acc1, 0, 0, 0);
        }
    };

    issue(0, Ga0, Ga1);
    dostore(0, 0, Ga0, Ga1);           // prologue: one vmcnt stall, only here
    issue(1, Gb0, Gb1);
#pragma unroll
    for (int k = 0; k < 9; ++k) {
        lgkm_barrier();                // S[k&1] visible; gathers keep flying
        mfma_step(k, k & 1);
        if ((k & 1) == 0) {
            if (k < 7) issue(k + 2, Ga0, Ga1);      // buf (k+2)&1 == 0
            if (k < 8) dostore(k + 1, (k + 1) & 1, Gb0, Gb1);
        } else {
            if (k < 7) issue(k + 2, Gb0, Gb1);
            if (k < 8) dostore(k + 1, (k + 1) & 1, Ga0, Ga1);
        }
    }

    // epilogue: C/D col=lane&15 (pos), row=(lane>>4)*4+reg (o)
#pragma unroll
    for (int nt = 0; nt < 2; ++nt) {
        floatx4 av = nt ? acc1 : acc0;
#pragma unroll
        for (int r = 0; r < 4; ++r) {
            int o = wv * 16 + q * 4 + r;
            out[(((size_t)b * OC + o) * HO + h) * WO + w0 + nt * 16 + m16] = av[r];
        }
    }
}

// ---------------------------------------------------------------------------
extern "C" void kernel_launch(void* const* d_in, const int* in_sizes, int n_in,
                              void* d_out, int out_size, void* d_ws, size_t ws_size,
                              hipStream_t stream)
{
    const float* x      = (const float*)d_in[0];
    const float* w_off  = (const float*)d_in[1];
    const float* b_off  = (const float*)d_in[2];
    const float* w_msk  = (const float*)d_in[3];
    const float* b_msk  = (const float*)d_in[4];
    const float* w_conv = (const float*)d_in[5];
    float* out = (float*)d_out;

    // workspace (~33.7 MB): xP f16-pair uints, Wom, W2
    unsigned int* xP = (unsigned int*)d_ws;                       // 8*HW*64 * 4B
    unsigned short* Wom = (unsigned short*)(xP + (size_t)BB * HW * 64); // 32*576
    unsigned short* W2 = Wom + 32 * 576;                          // 36864

    prep<<<dim3(2264), dim3(256), 0, stream>>>(x, w_off, w_msk, w_conv,
                                               xP, Wom, W2);
    fused<<<dim3(2048), dim3(256), 0, stream>>>(xP, Wom, W2,
                                                b_off, b_msk, out);
}

// Round 3
// 141.613 us; speedup vs baseline: 1.0968x; 1.0280x over previous
//
#include <hip/hip_runtime.h>
#include <hip/hip_fp16.h>
#include <math.h>

#define BB 8
#define CC 64
#define HH 128
#define WW 128
#define HO 64
#define WO 128
#define OC 64
#define HW (HH * WW)

typedef __attribute__((ext_vector_type(4))) float floatx4;
typedef __attribute__((ext_vector_type(8))) _Float16 half8;

__device__ __forceinline__ unsigned short f2h(float f) {
    __half h = __float2half(f);
    return __builtin_bit_cast(unsigned short, h);
}
__device__ __forceinline__ unsigned int packpair(float a, float b) {
    __half2 h = __floats2half2_rn(a, b);   // v_cvt_pkrtz_f16_f32, lo=a hi=b
    return __builtin_bit_cast(unsigned int, h);
}
// Barrier that drains ONLY LDS ops: global loads stay in flight across it.
__device__ __forceinline__ void lgkm_barrier() {
    asm volatile("s_waitcnt lgkmcnt(0)" ::: "memory");
    __builtin_amdgcn_s_barrier();
}

// ---------------------------------------------------------------------------
// Kernel A (prep) — unchanged from round 2 (isolate the fused delta):
//  blocks 0..2047   : transpose x -> xP[b][y][w][c] = (f16 col w, f16 col w+1)
//  blocks 2048..2119: Wom[32][576] f16
//  blocks 2120..2263: W2[k][o][c] f16
// ---------------------------------------------------------------------------
__global__ __launch_bounds__(256) void prep(
    const float* __restrict__ x,
    const float* __restrict__ w_off, const float* __restrict__ w_msk,
    const float* __restrict__ w_conv,
    unsigned int* __restrict__ xP,
    unsigned short* __restrict__ Wom, unsigned short* __restrict__ W2)
{
    __shared__ float T[64][77];        // odd stride: col reads conflict-free
    int tid = threadIdx.x, bx = blockIdx.x;
    if (bx < 2048) {
        int wh = bx & 1, b = (bx >> 1) & 7, y = bx >> 4;
        int w0 = wh << 6;
        const float* xb = x + (((size_t)b * CC) * HH + y) * WW + w0;
#pragma unroll
        for (int i = 0; i < 4; ++i) {
            int idx = i * 256 + tid;             // 0..1023
            int cch = idx >> 4, f4 = (idx & 15) << 2;
            floatx4 v = *(const floatx4*)(xb + (size_t)cch * HW + f4);
            T[cch][f4 + 0] = v.x;
            T[cch][f4 + 1] = v.y;
            T[cch][f4 + 2] = v.z;
            T[cch][f4 + 3] = v.w;
        }
        if (tid < 64) {
            float e = 0.0f;
            if (w0 + 64 < WW) e = xb[(size_t)tid * HW + 64];
            T[tid][64] = e;
        }
        __syncthreads();
        int ch = tid & 63;
        int wb = (tid >> 6) << 4;
        size_t base = ((((size_t)b * HH + y) * WW) + w0 + wb) * 64 + ch;
#pragma unroll
        for (int j = 0; j < 4; ++j) {
            int wl = wb + 4 * j;
            float a0 = T[ch][wl + 0];
            float a1 = T[ch][wl + 1];
            float a2 = T[ch][wl + 2];
            float a3 = T[ch][wl + 3];
            float a4 = T[ch][wl + 4];
            xP[base + (size_t)(4 * j + 0) * 64] = packpair(a0, a1);
            xP[base + (size_t)(4 * j + 1) * 64] = packpair(a1, a2);
            xP[base + (size_t)(4 * j + 2) * 64] = packpair(a2, a3);
            xP[base + (size_t)(4 * j + 3) * 64] = packpair(a3, a4);
        }
    } else if (bx < 2120) {
        int i = (bx - 2048) * 256 + tid;     // < 18432 = 32*576
        int chn = i / 576, kk = i % 576;
        int xs = kk >> 6, cc = kk & 63;
        float v = 0.0f;
        if (chn < 18)      v = w_off[(chn * CC + cc) * 9 + xs];
        else if (chn < 27) v = w_msk[((chn - 18) * CC + cc) * 9 + xs];
        Wom[i] = f2h(v);
    } else {
        int i = (bx - 2120) * 256 + tid;     // < 36864
        int k = i % 9, cc = (i / 9) % CC, o = i / (CC * 9);
        W2[((size_t)k * OC + o) * CC + cc] = f2h(w_conv[i]);
    }
}

// ---------------------------------------------------------------------------
// Kernel B: fused om-GEMM + coeff epilogue + deformable sampling + main MFMA.
//
// Round-3 fix: W2 (af) loads rotated 2 taps AHEAD of use. vmcnt is an
// in-order FIFO: in round 2 af(k) was issued AFTER gathers(k+1), so the
// s_waitcnt before MFMA(k) (waiting on af) drained the next tap's gathers
// -> full L2 latency exposed every tap. Now af(k) is issued BEFORE G(k),
// so dostore(k)'s wait on G(k) retires af(k) for free and MFMA(k) issues
// with zero vmem wait while G(k+1),G(k+2),af(k+1),af(k+2) stay in flight.
// ---------------------------------------------------------------------------
__global__ __launch_bounds__(256, 4) void fused(
    const unsigned int* __restrict__ xP,
    const unsigned short* __restrict__ Wom, const unsigned short* __restrict__ W2,
    const float* __restrict__ b_off, const float* __restrict__ b_msk,
    float* __restrict__ out)
{
    __shared__ __align__(16) char lds[18304];
    typedef _Float16 XsRow[34][72];
    XsRow* Xs = (XsRow*)lds;                                        // [3][34][72]
    unsigned short (*S)[32][64] = (unsigned short(*)[32][64])lds;   // [2][32][64]
    uint2* metaC = (uint2*)(lds + 8192);                            // 288*8
    uint2* metaR = (uint2*)(lds + 10496);                           // 288*8
    float (*omr)[33] = (float(*)[33])(lds + 14720);                 // [27][33]

    int tid = threadIdx.x;
    int lane = tid & 63;
    int wv = __builtin_amdgcn_readfirstlane(tid >> 6);
    int bx = blockIdx.x;               // 2048 = 8b * 64h * 4wt
    int b = bx & 7;
    int rest = bx >> 3;
    int h = rest >> 2;
    int w0 = (rest & 3) * 32;
    int h2 = 2 * h - 1;
    int m16 = lane & 15, q = lane >> 4;

    const unsigned int* xPb_u = xP + (size_t)b * HW * 64;

    // ---- phase 1: stage slab from xP pair-lows (uint4 coalesced) ----
    for (int u = tid; u < 1632; u += 256) {      // 1632 = 3*34*16
        int ky = u / 544;
        int rem = u - ky * 544;
        int col = rem >> 4, c4 = rem & 15;
        int hy = h2 + ky, wc = w0 - 1 + col;
        unsigned int lo0 = 0u, lo1 = 0u;
        if ((unsigned)hy < (unsigned)HH && (unsigned)wc < (unsigned)WW) {
            const uint4 g = *(const uint4*)(xPb_u + ((size_t)hy * WW + wc) * 64 + c4 * 4);
            lo0 = (g.x & 0xffffu) | (g.y << 16);
            lo1 = (g.z & 0xffffu) | (g.w << 16);
        }
        uint2* dst = (uint2*)((unsigned short*)lds + ((ky * 34 + col) * 72 + c4 * 4));
        *dst = make_uint2(lo0, lo1);
    }
    lgkm_barrier();

    // ---- phase 2: om GEMM (wave = 2 Mtiles x 2 Ntiles, K=576) ----
    {
        int mt = wv & 1, nt = wv >> 1;
        floatx4 a = (floatx4){0.f, 0.f, 0.f, 0.f};
        const _Float16* wa = (const _Float16*)Wom + (mt * 16 + m16) * 576 + q * 8;
#pragma unroll
        for (int t = 0; t < 18; ++t) {
            int xs = t >> 1, ky = xs / 3, kx = xs % 3;
            half8 af = *(const half8*)(wa + t * 32);
            half8 bf = *(const half8*)&Xs[ky][nt * 16 + m16 + kx][(t & 1) * 32 + q * 8];
            a = __builtin_amdgcn_mfma_f32_16x16x32_f16(af, bf, a, 0, 0, 0);
        }
#pragma unroll
        for (int r = 0; r < 4; ++r) {
            int chn = mt * 16 + q * 4 + r;
            if (chn < 27) omr[chn][nt * 16 + m16] = a[r];
        }
    }
    lgkm_barrier();   // omr ready; Xs reads done (meta/S may overlay)

    // ---- phase 3: coeffs (half2) + packed row byte-offsets per (tap,pos) ----
    for (int u = tid; u < 288; u += 256) {
        int kk = u >> 5, pos = u & 31;
        float offy = omr[2 * kk][pos] + b_off[2 * kk];
        float offx = omr[2 * kk + 1][pos] + b_off[2 * kk + 1];
        float mk = 1.0f / (1.0f + __expf(-(omr[18 + kk][pos] + b_msk[kk])));
        float py = offy + (float)(kk / 3) + (float)h2;
        float px = offx + (float)(kk % 3) + (float)(w0 + pos - 1);

        float y0f = floorf(py), x0f = floorf(px);
        float dy = py - y0f, dx = px - x0f;
        int y0 = (int)y0f, x0 = (int)x0f;
        int y1 = y0 + 1, x1 = x0 + 1;
        bool vy0 = (unsigned)y0 < (unsigned)HH;
        bool vy1 = (unsigned)y1 < (unsigned)HH;
        bool vx0 = (unsigned)x0 < (unsigned)WW;
        bool vx1 = (unsigned)x1 < (unsigned)WW;
        float w00 = (1.0f - dy) * (1.0f - dx) * ((vy0 && vx0) ? mk : 0.0f);
        float w01 = (1.0f - dy) * dx          * ((vy0 && vx1) ? mk : 0.0f);
        float w10 = dy * (1.0f - dx)          * ((vy1 && vx0) ? mk : 0.0f);
        float w11 = dy * dx                   * ((vy1 && vx1) ? mk : 0.0f);
        int xbase = min(max(x0, 0), WW - 2);
        bool s0 = x0 > xbase;
        bool s1 = x1 > xbase;
        float cxA = (s0 ? 0.f : w00) + (s1 ? 0.f : w01);
        float cyA = (s0 ? w00 : 0.f) + (s1 ? w01 : 0.f);
        float cxB = (s0 ? 0.f : w10) + (s1 ? 0.f : w11);
        float cyB = (s0 ? w10 : 0.f) + (s1 ? w11 : 0.f);
        int yc0 = min(max(y0, 0), HH - 1);
        int yc1 = min(max(y1, 0), HH - 1);

        __half2 hA = __floats2half2_rn(cxA, cyA);
        __half2 hB = __floats2half2_rn(cxB, cyB);
        metaC[u] = make_uint2(__builtin_bit_cast(unsigned int, hA),
                              __builtin_bit_cast(unsigned int, hB));
        metaR[u] = make_uint2((unsigned)(yc0 * WW + xbase) * 256u,
                              (unsigned)(yc1 * WW + xbase) * 256u);
    }
    lgkm_barrier();

    // ---- phase 4: 2-deep pipelined sampling + main MFMA ----
    int p0 = wv * 8;                   // my 8 positions
    const char* xPb = (const char*)xPb_u;
    unsigned int voff = 4u * (unsigned)lane;
    floatx4 acc0 = (floatx4){0.f, 0.f, 0.f, 0.f};
    floatx4 acc1 = (floatx4){0.f, 0.f, 0.f, 0.f};

    unsigned int Ga0[8], Ga1[8], Gb0[8], Gb1[8];
    half8 afr[3][2];                   // rotating W2 prefetch, 2 taps ahead
    const _Float16* W2w = (const _Float16*)W2 + ((size_t)wv * 16 + m16) * CC + q * 8;

    auto loadaf = [&](int k, int slot) {
#pragma unroll
        for (int s = 0; s < 2; ++s)
            afr[slot][s] = *(const half8*)(W2w + (size_t)k * (OC * CC) + s * 32);
    };
    auto issue = [&](int k, unsigned int (&A0)[8], unsigned int (&A1)[8]) {
#pragma unroll
        for (int i = 0; i < 8; ++i) {
            uint2 zw = metaR[k * 32 + p0 + i];           // broadcast ds_read_b64
            const char* r0 = xPb + (unsigned)__builtin_amdgcn_readfirstlane((int)zw.x);
            const char* r1 = xPb + (unsigned)__builtin_amdgcn_readfirstlane((int)zw.y);
            A0[i] = *(const unsigned int*)(r0 + voff);   // saddr + shared voffset
            A1[i] = *(const unsigned int*)(r1 + voff);
        }
    };
    auto dostore = [&](int k, int buf, unsigned int (&A0)[8], unsigned int (&A1)[8]) {
#pragma unroll
        for (int i = 0; i < 8; ++i) {
            uint2 cf = metaC[k * 32 + p0 + i];           // broadcast ds_read_b64
            __half2 hA = __builtin_bit_cast(__half2, cf.x);
            __half2 hB = __builtin_bit_cast(__half2, cf.y);
            __half2 g0 = __builtin_bit_cast(__half2, A0[i]);
            __half2 g1 = __builtin_bit_cast(__half2, A1[i]);
            __half2 p = __hfma2(hA, g0, __hmul2(hB, g1));   // v_pk_fma_f16
            __half sv = __hadd(__low2half(p), __high2half(p));
            int pos = p0 + i;
            S[buf][pos][((lane >> 3) ^ (pos & 7)) * 8 + (lane & 7)] =
                __builtin_bit_cast(unsigned short, sv);
        }
    };
    auto mfma_step = [&](int k, int buf, int slot) {
#pragma unroll
        for (int s = 0; s < 2; ++s) {
            half8 af = afr[slot][s];
            int cb = ((q + 4 * s) ^ (m16 & 7)) * 8;
            half8 bf0 = *(const half8*)&S[buf][m16][cb];
            half8 bf1 = *(const half8*)&S[buf][16 + m16][cb];
            acc0 = __builtin_amdgcn_mfma_f32_16x16x32_f16(af, bf0, acc0, 0, 0, 0);
            acc1 = __builtin_amdgcn_mfma_f32_16x16x32_f16(af, bf1, acc1, 0, 0, 0);
        }
    };

    // prologue. FIFO order: af(0) af(1) G(0) [wait G(0) retires af0,af1] G(1)
    loadaf(0, 0);
    loadaf(1, 1);
    issue(0, Ga0, Ga1);
    dostore(0, 0, Ga0, Ga1);
    issue(1, Gb0, Gb1);
#pragma unroll
    for (int k = 0; k < 9; ++k) {
        lgkm_barrier();                // S[k&1] visible; gathers keep flying
        if (k < 7) {
            loadaf(k + 2, (k + 2) % 3);              // af ahead of its G
            if ((k & 1) == 0) issue(k + 2, Ga0, Ga1);
            else              issue(k + 2, Gb0, Gb1);
        }
        mfma_step(k, k & 1, k % 3);                  // no vmem wait here
        if (k < 8) {
            if ((k & 1) == 0) dostore(k + 1, 1, Gb0, Gb1);
            else              dostore(k + 1, 0, Ga0, Ga1);
        }
    }

    // epilogue: C/D col=lane&15 (pos), row=(lane>>4)*4+reg (o)
#pragma unroll
    for (int nt = 0; nt < 2; ++nt) {
        floatx4 av = nt ? acc1 : acc0;
#pragma unroll
        for (int r = 0; r < 4; ++r) {
            int o = wv * 16 + q * 4 + r;
            out[(((size_t)b * OC + o) * HO + h) * WO + w0 + nt * 16 + m16] = av[r];
        }
    }
}

// ---------------------------------------------------------------------------
extern "C" void kernel_launch(void* const* d_in, const int* in_sizes, int n_in,
                              void* d_out, int out_size, void* d_ws, size_t ws_size,
                              hipStream_t stream)
{
    const float* x      = (const float*)d_in[0];
    const float* w_off  = (const float*)d_in[1];
    const float* b_off  = (const float*)d_in[2];
    const float* w_msk  = (const float*)d_in[3];
    const float* b_msk  = (const float*)d_in[4];
    const float* w_conv = (const float*)d_in[5];
    float* out = (float*)d_out;

    // workspace (~33.7 MB): xP f16-pair uints, Wom, W2
    unsigned int* xP = (unsigned int*)d_ws;                       // 8*HW*64 * 4B
    unsigned short* Wom = (unsigned short*)(xP + (size_t)BB * HW * 64); // 32*576
    unsigned short* W2 = Wom + 32 * 576;                          // 36864

    prep<<<dim3(2264), dim3(256), 0, stream>>>(x, w_off, w_msk, w_conv,
                                               xP, Wom, W2);
    fused<<<dim3(2048), dim3(256), 0, stream>>>(xP, Wom, W2,
                                                b_off, b_msk, out);
}